// Round 3
// baseline (174.321 us; speedup 1.0000x reference)
//
#include <hip/hip_runtime.h>

#define IMG_H 512
#define IMG_W 512
#define BATCH 32
#define TW 256            // columns per block strip (1 col/thread)
#define TH 32             // output rows per block
#define NROWS (TH + 6)    // 38 input rows
#define PITCH 264         // float2 slots per LDS row (262 needed, pad to 264)
#define NBLK (2 * 16 * 32)  // 1024 blocks

// One input row's work: horizontal 7-tap from LDS, vertical scatter into the
// mod-7 register ring, emit completed output row. RR/LO/HI/RBASE are
// compile-time at every expansion site so acc[] indices fold to registers.
#define ROW_BODY(RR, BUF, RBASE, LO, HI)                                      \
  {                                                                           \
    float hx = 0.f, hy = 0.f, hxx = 0.f, hyy = 0.f, hxy = 0.f;                \
    _Pragma("unroll") for (int k = 0; k < 7; ++k) {                           \
      const float2 p = sbuf[BUF][(RR)*PITCH + t + k];                         \
      const float wx = w[k] * p.x;                                            \
      const float wy = w[k] * p.y;                                            \
      hx = fmaf(w[k], p.x, hx);                                               \
      hy = fmaf(w[k], p.y, hy);                                               \
      hxx = fmaf(wx, p.x, hxx);                                               \
      hyy = fmaf(wy, p.y, hyy);                                               \
      hxy = fmaf(wx, p.y, hxy);                                               \
    }                                                                         \
    _Pragma("unroll") for (int tt = 0; tt < 7; ++tt) {                        \
      if ((!(LO) || (RR) >= tt) && (!(HI) || (RBASE) + (RR)-tt < TH)) {       \
        const int slot = (((RR)-tt) % 7 + 7) % 7;                             \
        const float wt = w[tt];                                               \
        acc[slot][0] = fmaf(wt, hx, acc[slot][0]);                            \
        acc[slot][1] = fmaf(wt, hy, acc[slot][1]);                            \
        acc[slot][2] = fmaf(wt, hxx, acc[slot][2]);                           \
        acc[slot][3] = fmaf(wt, hyy, acc[slot][3]);                           \
        acc[slot][4] = fmaf(wt, hxy, acc[slot][4]);                           \
      }                                                                       \
    }                                                                         \
    if ((!(LO) || (RR) >= 6) && (!(HI) || (RBASE) + (RR)-6 < TH)) {           \
      const int slot = ((RR) + 1) % 7;                                        \
      const float mu_x = acc[slot][0];                                        \
      const float mu_y = acc[slot][1];                                        \
      const float mx2 = mu_x * mu_x;                                          \
      const float my2 = mu_y * mu_y;                                          \
      const float mxy = mu_x * mu_y;                                          \
      const float sxx = acc[slot][2] - mx2;                                   \
      const float syy = acc[slot][3] - my2;                                   \
      const float sxy = acc[slot][4] - mxy;                                   \
      const float num = (2.f * mxy + 1e-4f) * (2.f * sxy + 9e-4f);            \
      const float den = (mx2 + my2 + 1e-4f) * (sxx + syy + 9e-4f);            \
      tsum += num * __builtin_amdgcn_rcpf(den);                               \
      acc[slot][0] = acc[slot][1] = acc[slot][2] = acc[slot][3] =             \
          acc[slot][4] = 0.f;                                                 \
    }                                                                         \
  }

__global__ __launch_bounds__(256, 4) void ssim_main(
    const float* __restrict__ X, const float* __restrict__ Y,
    const float* __restrict__ K, float* __restrict__ partials) {
  __shared__ float2 sbuf[2][7 * PITCH];   // 29568 B: double-buffered 7-row chunks
  __shared__ float wsum[4];

  const int t = threadIdx.x;
  const int x0 = blockIdx.x * TW;
  const int y0 = blockIdx.y * TH;
  const size_t img = (size_t)IMG_H * IMG_W;
  const float* Xb = X + blockIdx.z * img;
  const float* Yb = Y + blockIdx.z * img;

  // Exact separable 1D weights from center row of the 7x7 kernel.
  float w[7];
  {
    float rs = 0.f;
#pragma unroll
    for (int j = 0; j < 7; ++j) { w[j] = K[3 * 7 + j]; rs += w[j]; }
    const float inv = 1.f / rs;
#pragma unroll
    for (int j = 0; j < 7; ++j) w[j] *= inv;
  }

  const int g1 = x0 - 3 + t;
  const bool ok1 = (unsigned)g1 < (unsigned)IMG_W;
  const int g2 = g1 + TW;
  const bool ok2 = (t < 6) && ((unsigned)g2 < (unsigned)IMG_W);

  float acc[7][5];
#pragma unroll
  for (int s = 0; s < 7; ++s)
#pragma unroll
    for (int c = 0; c < 5; ++c) acc[s][c] = 0.f;
  float tsum = 0.f;

  // 7-row chunk prefetch registers (x/y main + halo lanes)
  float pxa[7], pya[7], pxb[7], pyb[7];

  auto load_chunk = [&](int c0) {  // tile rows c0..c0+6 -> image row y0-3+r
#pragma unroll
    for (int i = 0; i < 7; ++i) {
      const int gy = y0 - 3 + c0 + i;
      pxa[i] = pya[i] = pxb[i] = pyb[i] = 0.f;
      if ((unsigned)gy < (unsigned)IMG_H) {
        const float* xr_ = Xb + (size_t)gy * IMG_W;
        const float* yr_ = Yb + (size_t)gy * IMG_W;
        if (ok1) { pxa[i] = xr_[g1]; pya[i] = yr_[g1]; }
        if (ok2) { pxb[i] = xr_[g2]; pyb[i] = yr_[g2]; }
      }
    }
  };

  auto store_chunk = [&](int buf) {
#pragma unroll
    for (int i = 0; i < 7; ++i) {
      sbuf[buf][i * PITCH + t] = make_float2(pxa[i], pya[i]);
      if (t < 6) sbuf[buf][i * PITCH + TW + t] = make_float2(pxb[i], pyb[i]);
    }
  };

  // ---- chunk 0 (lower-bound guards, compile-time) ----
  load_chunk(0);
  store_chunk(0);
  __syncthreads();
  load_chunk(7);                         // prefetch chunk 1; drains at NEXT barrier
#pragma unroll
  for (int rr = 0; rr < 7; ++rr) ROW_BODY(rr, 0, 0, true, false);

  // ---- chunks 1..4 (steady state, no guards, 1 barrier per 7 rows) ----
  for (int ck = 1; ck <= 4; ++ck) {
    const int buf = ck & 1;
    store_chunk(buf);                    // regs for chunk ck -> LDS
    __syncthreads();                     // also drains chunk-ck+?? loads (issued 7 rows ago)
    load_chunk(7 * (ck + 1));            // prefetch chunk ck+1
#pragma unroll
    for (int rr = 0; rr < 7; ++rr) ROW_BODY(rr, buf, 0, false, false);
  }

  // ---- chunk 5 (rows 35..37 only; upper-bound guards, compile-time) ----
  store_chunk(1);
  __syncthreads();
#pragma unroll
  for (int rr = 0; rr < 3; ++rr) ROW_BODY(rr, 1, 35, false, true);

  // block reduction -> one plain store per block (no atomics, no fences)
#pragma unroll
  for (int off = 32; off > 0; off >>= 1) tsum += __shfl_down(tsum, off);
  if ((t & 63) == 0) wsum[t >> 6] = tsum;
  __syncthreads();
  if (t == 0) {
    const int bid = blockIdx.x + 2 * (blockIdx.y + 16 * blockIdx.z);
    partials[bid] = wsum[0] + wsum[1] + wsum[2] + wsum[3];
  }
}

__global__ __launch_bounds__(256) void ssim_reduce(
    const float* __restrict__ partials, float* __restrict__ out) {
  __shared__ double wsum[4];
  const int t = threadIdx.x;
  double s = 0.0;
#pragma unroll
  for (int i = 0; i < NBLK / 256; ++i) s += (double)partials[t + 256 * i];
#pragma unroll
  for (int off = 32; off > 0; off >>= 1) s += __shfl_down(s, off);
  if ((t & 63) == 0) wsum[t >> 6] = s;
  __syncthreads();
  if (t == 0)
    out[0] = (float)((wsum[0] + wsum[1] + wsum[2] + wsum[3]) *
                     (1.0 / (double)((size_t)BATCH * IMG_H * IMG_W)));
}

extern "C" void kernel_launch(void* const* d_in, const int* in_sizes, int n_in,
                              void* d_out, int out_size, void* d_ws, size_t ws_size,
                              hipStream_t stream) {
  const float* X = (const float*)d_in[0];
  const float* Y = (const float*)d_in[1];
  const float* K = (const float*)d_in[2];
  float* out = (float*)d_out;
  float* partials = (float*)d_ws;   // NBLK floats, all written every launch

  dim3 grid(IMG_W / TW, IMG_H / TH, BATCH);  // (2, 16, 32) = 1024 blocks
  hipLaunchKernelGGL(ssim_main, grid, dim3(256), 0, stream, X, Y, K, partials);
  hipLaunchKernelGGL(ssim_reduce, dim3(1), dim3(256), 0, stream, partials, out);
}